// Round 7
// baseline (3416.566 us; speedup 1.0000x reference)
//
#include <hip/hip_runtime.h>
#include <hip/hip_bf16.h>

#define T_STEPS 512
#define D_IN 75
#define H_DIM 512
#define G_DIM 2048
#define NCLS_ 11
#define NKK 19           // 16 h-ktiles + 3 x-ktiles (K = 512 + 96pad = 608)
#define NCH 16           // chains = batch groups of 16 rows
#define NJ 16            // column groups (32 h-cols each)

typedef __attribute__((ext_vector_type(8))) short short8;
typedef __attribute__((ext_vector_type(4))) float f32x4;

__device__ __forceinline__ unsigned short f2b(float f) {
  unsigned int u = __float_as_uint(f);
  unsigned int r = (u + 0x7fffu + ((u >> 16) & 1u)) >> 16;
  return (unsigned short)r;
}
__device__ __forceinline__ float b2f(unsigned short u) {
  return __uint_as_float(((unsigned int)u) << 16);
}
__device__ __forceinline__ float softplusf(float v) {
  return (v > 20.f) ? v : log1pf(__expf(v));
}
__device__ __forceinline__ float sigmf(float v) {
  return 1.f / (1.f + __expf(-v));
}
__device__ __forceinline__ float tanhf_(float v) {
  float a = fabsf(v);
  float e = __expf(-2.f * a);
  float r = (1.f - e) / (1.f + e);
  return copysignf(r, v);
}
__device__ __forceinline__ unsigned long long pack4(const unsigned short* v) {
  return (unsigned long long)v[0] | ((unsigned long long)v[1] << 16) |
         ((unsigned long long)v[2] << 32) | ((unsigned long long)v[3] << 48);
}

#define ALD(p) __hip_atomic_load((p), __ATOMIC_RELAXED, __HIP_MEMORY_SCOPE_AGENT)
#define AST(p, v) __hip_atomic_store((p), (v), __ATOMIC_RELAXED, __HIP_MEMORY_SCOPE_AGENT)

// ---------------------------------------------------------------------------
// Prologue: sample W = mu + softplus(rho)*eps for [w_hh; w_ih; 0pad] (608x2048)
// and pack into MFMA B-fragment chunks. (Unchanged from round 6.)
// ---------------------------------------------------------------------------
__global__ __launch_bounds__(64) void pack_w_kernel(
    const float* __restrict__ wih_mu, const float* __restrict__ wih_rho, const float* __restrict__ eps_ih,
    const float* __restrict__ whh_mu, const float* __restrict__ whh_rho, const float* __restrict__ eps_hh,
    unsigned short* __restrict__ wpack)
{
  int c = blockIdx.x;             // 0..2431
  int j = c / (8 * NKK);
  int r = c % (8 * NKK);
  int wv = r / NKK;
  int kk = r % NKK;
  int l = threadIdx.x;
  int s = l & 15, grp = l >> 4;
  int q = s >> 2, cc = s & 3;
  int n = q * 512 + j * 32 + wv * 4 + cc;
  unsigned short vs[8];
#pragma unroll
  for (int e = 0; e < 8; ++e) {
    int k = kk * 32 + grp * 8 + e;
    float val = 0.f;
    if (k < 512) {
      int idx = k * G_DIM + n;
      val = whh_mu[idx] + softplusf(whh_rho[idx]) * eps_hh[idx];
    } else if (k < 512 + D_IN) {
      int idx = (k - 512) * G_DIM + n;
      val = wih_mu[idx] + softplusf(wih_rho[idx]) * eps_ih[idx];
    }
    vs[e] = f2b(val);
  }
  unsigned long long u0 = pack4(vs);
  unsigned long long u1 = pack4(vs + 4);
  unsigned long long* dst = (unsigned long long*)wpack + (size_t)c * 128 + l * 2;
  dst[0] = u0;
  dst[1] = u1;
}

// ---------------------------------------------------------------------------
// Persistent scan, 2 phase-shifted chains per block.
// 128 blocks: m = bid&7 (XCD-clustered pair), j = bid>>3.
// Block (m,j) runs chains gA=2m, gB=2m+1 (16 batch rows each), cols [j*32,+32).
// 4 waves x 8 cols (2 ct tiles); W regs (152 VGPR/wave) SHARED by both chains.
// Per chain step: per-wave poll of the 4 source blocks' 16 wave-flags ->
// stage 4 chunks (8 sc1 ULL) -> barrier -> 38 MFMA (x frags in regs) ->
// in-wave epilogue -> per-wave publish (16 lanes x 16B) + flag.
// While chain A's flags/data propagate through the LLC, chain B computes.
// Overwrite safety: hstage[c] rewrite at iter t is ordered after the OTHER
// chain's barrier of iter t-1/t, which all waves reach only after finishing
// their MFMA reads of hstage[c] (alternating-barrier argument).
// Buffer safety: block X publishes h(t+1) only after ALL its waves' polls
// passed (barrier), which requires every block to have published h(t), i.e.
// finished staging h(t-1) out of the parity buffer X overwrites.
// ---------------------------------------------------------------------------
struct SmemLoop {
  unsigned short hstage[2][16][64][8]; // 32KB [chain][chunk][lane][e]
  float gatesT[4][2][16][20];          // 10KB [wave][ct][colS][rowM pad20]
  unsigned short hq[4][16][8];         // 1KB  [wave][row][e]
};
union Smem {
  SmemLoop s;
  unsigned short zbuf[16][512];        // 16KB (post-loop FC only)
};

__global__ __launch_bounds__(256, 1) void lstm_scan_kernel(
    const float* __restrict__ x,
    const unsigned short* __restrict__ wpack,
    const float* __restrict__ b_mu, const float* __restrict__ b_rho, const float* __restrict__ eps_b,
    const float* __restrict__ fc_w, const float* __restrict__ fc_b,
    unsigned long long* __restrict__ hbuf, int* __restrict__ flags,
    float* __restrict__ out)
{
  __shared__ Smem sm;

  const int bid = blockIdx.x;
  const int m = bid & 7, j = bid >> 3;      // XCD-clustered chain pairs
  const int gA = 2 * m, gB = 2 * m + 1;
  const int tid = threadIdx.x;
  const int w = tid >> 6, lane = tid & 63;
  const int srow = lane & 15, grp = lane >> 4;

  // ---- stationary W fragments (2 ct x 19 ktiles x 16B/lane) — shared by A,B
  short8 Wreg[2][NKK];
  {
    const short8* wp = (const short8*)wpack;
#pragma unroll
    for (int ct = 0; ct < 2; ++ct) {
      const int cj = (j * 8 + w * 2 + ct) * NKK;
#pragma unroll
      for (int kk = 0; kk < NKK; ++kk)
        Wreg[ct][kk] = wp[(size_t)(cj + kk) * 64 + lane];
    }
  }
  // ---- sampled bias (lane role in epilogue: row=srow, cc=grp) — shared
  float bias_[2][4];
#pragma unroll
  for (int ct = 0; ct < 2; ++ct)
#pragma unroll
    for (int q = 0; q < 4; ++q) {
      int idx = q * 512 + j * 32 + (w * 2 + ct) * 4 + grp;
      bias_[ct][q] = b_mu[idx] + softplusf(b_rho[idx]) * eps_b[idx];
    }

  float cstA[2] = {0.f, 0.f}, cstB[2] = {0.f, 0.f};

  // ---- publish h_0 = 0 for both chains (per-wave slice: lanes 0-15)
#pragma unroll
  for (int c = 0; c < 2; ++c) {
    int g = 2 * m + c;
    unsigned long long* hb0 = hbuf + ((size_t)(0 * NCH + g)) * 2048;
    if (lane < 16) {
      unsigned long long* dst = hb0 + (size_t)j * 128 + (w * 16 + lane) * 2;
      AST(dst, 0ull);
      AST(dst + 1, 0ull);
    }
  }
  asm volatile("s_waitcnt vmcnt(0)" ::: "memory");
  if (lane == 0) {
    AST(&flags[((gA * 16 + j) * 4 + w) * 16], 1);
    AST(&flags[((gB * 16 + j) * 4 + w) * 16], 1);
  }

  // ---- one chain step (inlined twice per iteration)
  auto step_chain = [&](int g, float* cst, int ci, int t) {
    // issue x loads first (plain cached; independent of flags)
    const float* xr = x + (size_t)(g * 16 + srow) * (T_STEPS * D_IN) + (size_t)t * D_IN;
    float xraw[24];
#pragma unroll
    for (int kx = 0; kx < 3; ++kx)
#pragma unroll
      for (int e = 0; e < 8; ++e) {
        int d = kx * 32 + grp * 8 + e;
        xraw[kx * 8 + e] = (d < D_IN) ? xr[d] : 0.f;
      }

    // per-wave poll: the 4 source blocks' 16 wave-flags (dup'd across lanes)
    {
      const int tgt = t + 1;
      const int l16 = lane & 15;
      const int* fp = &flags[((g * 16 + (w * 4 + (l16 >> 2))) * 4 + (l16 & 3)) * 16];
      while (true) {
        int f = ALD(fp);
        if (__all(f >= tgt)) break;
        __builtin_amdgcn_s_sleep(1);
      }
    }

    // stage this wave's 4 chunks (8 sc1 ULL loads back-to-back)
    const unsigned long long* hb = hbuf + ((size_t)((t & 1) * NCH + g)) * 2048;
    unsigned long long sv[8];
#pragma unroll
    for (int c8 = 0; c8 < 4; ++c8) {
      const unsigned long long* p = hb + (size_t)(w * 4 + c8) * 128 + lane * 2;
      sv[2 * c8]     = ALD(p);
      sv[2 * c8 + 1] = ALD(p + 1);
    }

    // convert x to bf16 frags while h loads are in flight
    short8 xf[3];
#pragma unroll
    for (int kx = 0; kx < 3; ++kx) {
      unsigned short vs[8];
#pragma unroll
      for (int e = 0; e < 8; ++e) vs[e] = f2b(xraw[kx * 8 + e]);
      union { unsigned long long u[2]; short8 v; } q;
      q.u[0] = pack4(vs);
      q.u[1] = pack4(vs + 4);
      xf[kx] = q.v;
    }

    // regs -> LDS hstage (vmcnt drain happens here)
#pragma unroll
    for (int c8 = 0; c8 < 4; ++c8) {
      unsigned long long* dp = (unsigned long long*)&sm.s.hstage[ci][w * 4 + c8][lane][0];
      dp[0] = sv[2 * c8];
      dp[1] = sv[2 * c8 + 1];
    }

    __syncthreads();   // chain-phase barrier

    // MFMA: 3 x-tiles (reg frags) + 16 h-tiles (LDS)
    f32x4 acc0 = {0.f, 0.f, 0.f, 0.f}, acc1 = {0.f, 0.f, 0.f, 0.f};
#pragma unroll
    for (int kx = 0; kx < 3; ++kx) {
      acc0 = __builtin_amdgcn_mfma_f32_16x16x32_bf16(xf[kx], Wreg[0][16 + kx], acc0, 0, 0, 0);
      acc1 = __builtin_amdgcn_mfma_f32_16x16x32_bf16(xf[kx], Wreg[1][16 + kx], acc1, 0, 0, 0);
    }
#pragma unroll
    for (int kk = 0; kk < 16; ++kk) {
      short8 a = *(const short8*)&sm.s.hstage[ci][kk][lane][0];
      acc0 = __builtin_amdgcn_mfma_f32_16x16x32_bf16(a, Wreg[0][kk], acc0, 0, 0, 0);
      acc1 = __builtin_amdgcn_mfma_f32_16x16x32_bf16(a, Wreg[1][kk], acc1, 0, 0, 0);
    }

    // epilogue: in-wave LDS transpose (no barrier), activations, c/h update
    *(f32x4*)&sm.s.gatesT[w][0][srow][grp * 4] = acc0;
    *(f32x4*)&sm.s.gatesT[w][1][srow][grp * 4] = acc1;
#pragma unroll
    for (int ct = 0; ct < 2; ++ct) {
      float vi = sm.s.gatesT[w][ct][grp + 0][srow] + bias_[ct][0];
      float vf = sm.s.gatesT[w][ct][grp + 4][srow] + bias_[ct][1];
      float vg = sm.s.gatesT[w][ct][grp + 8][srow] + bias_[ct][2];
      float vo = sm.s.gatesT[w][ct][grp + 12][srow] + bias_[ct][3];
      float ii = sigmf(vi), ff = sigmf(vf);
      float gg = tanhf_(vg), oo = sigmf(vo);
      float cn = ff * cst[ct] + ii * gg;
      cst[ct] = cn;
      sm.s.hq[w][srow][ct * 4 + grp] = f2b(oo * tanhf_(cn));
    }

    // per-wave publish: 16 lanes x 16B into chunk j, slot group w
    {
      unsigned long long* hbn = hbuf + ((size_t)(((t + 1) & 1) * NCH + g)) * 2048;
      if (lane < 16) {
        const unsigned long long* hp = (const unsigned long long*)&sm.s.hq[w][lane][0];
        unsigned long long u0 = hp[0], u1 = hp[1];
        unsigned long long* dst = hbn + (size_t)j * 128 + (w * 16 + lane) * 2;
        AST(dst, u0);
        AST(dst + 1, u1);
      }
      asm volatile("s_waitcnt vmcnt(0)" ::: "memory");
      if (lane == 0) AST(&flags[((g * 16 + j) * 4 + w) * 16], t + 2);
    }
  };

  for (int t = 0; t < T_STEPS; ++t) {
    step_chain(gA, cstA, 0, t);
    step_chain(gB, cstB, 1, t);
  }

  // ---- final FC: z = h_T @ fc_w^T + fc_b  (j==0 blocks; h_T in parity 0)
  if (j == 0) {
#pragma unroll 1
    for (int c = 0; c < 2; ++c) {
      int g = 2 * m + c;
      {
        const int tgt = T_STEPS + 1;
        const int* fp = &flags[((g * 16 + (lane >> 2)) * 4 + (lane & 3)) * 16];
        while (true) {
          int f = ALD(fp);
          if (__all(f >= tgt)) break;
          __builtin_amdgcn_s_sleep(1);
        }
      }
      __syncthreads();   // all waves past loop / previous chain's FC reads
      const unsigned long long* hb0 = hbuf + (size_t)g * 2048;
      for (int it = tid; it < 2048; it += 256) {
        unsigned long long v = ALD(hb0 + it);
        int kk = it >> 7, pos = it & 127;
        int l128 = pos >> 1, half = pos & 1;
        int row = l128 & 15, gsl = l128 >> 4;
        int k = kk * 32 + gsl * 8 + half * 4;
        *(unsigned long long*)&sm.zbuf[row][k] = v;
      }
      __syncthreads();
      for (int i = tid; i < 16 * NCLS_; i += 256) {
        int r = i / NCLS_, n = i % NCLS_;
        float s = fc_b[n];
        const float* fw = fc_w + n * H_DIM;
        for (int k = 0; k < H_DIM; ++k)
          s += b2f(sm.zbuf[r][k]) * fw[k];
        out[(g * 16 + r) * NCLS_ + n] = s;
      }
      __syncthreads();
    }
  }
}

// ---------------------------------------------------------------------------
extern "C" void kernel_launch(void* const* d_in, const int* in_sizes, int n_in,
                              void* d_out, int out_size, void* d_ws, size_t ws_size,
                              hipStream_t stream) {
  const float* x       = (const float*)d_in[0];
  const float* wih_mu  = (const float*)d_in[1];
  const float* wih_rho = (const float*)d_in[2];
  const float* eps_ih  = (const float*)d_in[3];
  const float* whh_mu  = (const float*)d_in[4];
  const float* whh_rho = (const float*)d_in[5];
  const float* eps_hh  = (const float*)d_in[6];
  const float* b_mu    = (const float*)d_in[7];
  const float* b_rho   = (const float*)d_in[8];
  const float* eps_b   = (const float*)d_in[9];
  const float* fc_w    = (const float*)d_in[10];
  const float* fc_b    = (const float*)d_in[11];

  // ws layout: wpack [0, 2490368) | hbuf [2490368, +524288) | flags [3014656, +65536)
  unsigned short* wpack = (unsigned short*)d_ws;
  unsigned long long* hbuf = (unsigned long long*)((char*)d_ws + 2490368);
  int* flags = (int*)((char*)d_ws + 3014656);

  hipMemsetAsync(flags, 0, 65536, stream);
  pack_w_kernel<<<NJ * 8 * NKK, 64, 0, stream>>>(wih_mu, wih_rho, eps_ih,
                                                 whh_mu, whh_rho, eps_hh, wpack);
  lstm_scan_kernel<<<128, 256, 0, stream>>>(x, wpack, b_mu, b_rho, eps_b,
                                            fc_w, fc_b, hbuf, flags,
                                            (float*)d_out);
}

// Round 8
// 2450.285 us; speedup vs baseline: 1.3944x; 1.3944x over previous
//
#include <hip/hip_runtime.h>
#include <hip/hip_bf16.h>

#define T_STEPS 512
#define D_IN 75
#define H_DIM 512
#define G_DIM 2048
#define NCLS_ 11
#define NKK 19           // 16 h-ktiles + 3 x-ktiles (K = 512 + 96pad = 608)
#define NG 8             // batch groups (32 rows each)
#define NJ 16            // column groups (32 h-cols each)

typedef __attribute__((ext_vector_type(8))) short short8;
typedef __attribute__((ext_vector_type(4))) float f32x4;
typedef __attribute__((ext_vector_type(4))) unsigned int u32x4;

__device__ __forceinline__ unsigned short f2b(float f) {
  unsigned int u = __float_as_uint(f);
  unsigned int r = (u + 0x7fffu + ((u >> 16) & 1u)) >> 16;
  return (unsigned short)r;
}
__device__ __forceinline__ float b2f(unsigned short u) {
  return __uint_as_float(((unsigned int)u) << 16);
}
__device__ __forceinline__ float softplusf(float v) {
  return (v > 20.f) ? v : log1pf(__expf(v));
}
__device__ __forceinline__ float sigmf(float v) {
  return 1.f / (1.f + __expf(-v));
}
__device__ __forceinline__ float tanhf_(float v) {
  float a = fabsf(v);
  float e = __expf(-2.f * a);
  float r = (1.f - e) / (1.f + e);
  return copysignf(r, v);
}
__device__ __forceinline__ unsigned long long pack4(const unsigned short* v) {
  return (unsigned long long)v[0] | ((unsigned long long)v[1] << 16) |
         ((unsigned long long)v[2] << 32) | ((unsigned long long)v[3] << 48);
}

#define ALD(p) __hip_atomic_load((p), __ATOMIC_RELAXED, __HIP_MEMORY_SCOPE_AGENT)
#define AST(p, v) __hip_atomic_store((p), (v), __ATOMIC_RELAXED, __HIP_MEMORY_SCOPE_AGENT)

// ---------------------------------------------------------------------------
// Prologue: sample W = mu + softplus(rho)*eps for [w_hh; w_ih; 0pad] (608x2048)
// and pack into MFMA B-fragment chunks. (Unchanged since round 1.)
// ---------------------------------------------------------------------------
__global__ __launch_bounds__(64) void pack_w_kernel(
    const float* __restrict__ wih_mu, const float* __restrict__ wih_rho, const float* __restrict__ eps_ih,
    const float* __restrict__ whh_mu, const float* __restrict__ whh_rho, const float* __restrict__ eps_hh,
    unsigned short* __restrict__ wpack)
{
  int c = blockIdx.x;             // 0..2431
  int j = c / (8 * NKK);
  int r = c % (8 * NKK);
  int wv = r / NKK;
  int kk = r % NKK;
  int l = threadIdx.x;
  int s = l & 15, grp = l >> 4;
  int q = s >> 2, cc = s & 3;
  int n = q * 512 + j * 32 + wv * 4 + cc;
  unsigned short vs[8];
#pragma unroll
  for (int e = 0; e < 8; ++e) {
    int k = kk * 32 + grp * 8 + e;
    float val = 0.f;
    if (k < 512) {
      int idx = k * G_DIM + n;
      val = whh_mu[idx] + softplusf(whh_rho[idx]) * eps_hh[idx];
    } else if (k < 512 + D_IN) {
      int idx = (k - 512) * G_DIM + n;
      val = wih_mu[idx] + softplusf(wih_rho[idx]) * eps_ih[idx];
    }
    vs[e] = f2b(val);
  }
  unsigned long long u0 = pack4(vs);
  unsigned long long u1 = pack4(vs + 4);
  unsigned long long* dst = (unsigned long long*)wpack + (size_t)c * 128 + l * 2;
  dst[0] = u0;
  dst[1] = u1;
}

// ---------------------------------------------------------------------------
// Persistent scan kernel (round-6 protocol, LDS-conflict-fixed).
// 128 blocks; g=bid&7 (XCD-clustered), j=bid>>3. 4 waves x 8 cols.
// Cross-block traffic: __hip_atomic_* AGENT only (proven). Per-wave flags on
// private 64B lines; per-wave publish; ONE barrier per step.
// Round-8 changes vs round 6:
//  - hstage LDS stores are single b128 stores (u32x4), not ULL pairs: the
//    b64-pair pattern (bank = 4*lane % 32) was an 8-way write conflict.
//  - x fragments are per-wave register-resident (each wave loads its own 6
//    frags; issued AFTER the staging drain, consumed next step). x_lds and
//    the wave-1 pipeline are deleted.
// ---------------------------------------------------------------------------
struct __align__(16) SmemLoop {
  unsigned short hstage[32][64][8];   // 32KB  staged h chunks, A-frag layout
  float gatesT[4][2][2][16][20];      // 20KB  [wave][ct][rg][slotN][rowM pad20]
  unsigned short hq[4][2][16][8];     // 2KB   [wave][rg][row][e] (16B rows)
};
union Smem {
  SmemLoop s;
  unsigned short zbuf[32][512];       // 32KB (post-loop FC only)
};

__global__ __launch_bounds__(256, 1) void lstm_scan_kernel(
    const float* __restrict__ x,
    const unsigned short* __restrict__ wpack,
    const float* __restrict__ b_mu, const float* __restrict__ b_rho, const float* __restrict__ eps_b,
    const float* __restrict__ fc_w, const float* __restrict__ fc_b,
    unsigned long long* __restrict__ hbuf, int* __restrict__ flags,
    float* __restrict__ out)
{
  __shared__ Smem sm;

  const int bid = blockIdx.x;
  const int g = bid & 7, j = bid >> 3;      // XCD-clustered groups
  const int tid = threadIdx.x;
  const int w = tid >> 6, lane = tid & 63;
  const int srow = lane & 15, grp = lane >> 4;

  // ---- stationary W fragments (2 ct x 19 ktiles x 16B per lane)
  short8 Wreg[2][NKK];
  {
    const short8* wp = (const short8*)wpack;
#pragma unroll
    for (int ct = 0; ct < 2; ++ct) {
      const int cj = (j * 8 + w * 2 + ct) * NKK;
#pragma unroll
      for (int kk = 0; kk < NKK; ++kk)
        Wreg[ct][kk] = wp[(size_t)(cj + kk) * 64 + lane];
    }
  }
  // ---- sampled bias (epilogue lane role: row=srow, cc=grp)
  float bias_[2][4];
#pragma unroll
  for (int ct = 0; ct < 2; ++ct)
#pragma unroll
    for (int q = 0; q < 4; ++q) {
      int idx = q * 512 + j * 32 + (w * 2 + ct) * 4 + grp;
      bias_[ct][q] = b_mu[idx] + softplusf(b_rho[idx]) * eps_b[idx];
    }

  float cst[2][2] = {{0.f, 0.f}, {0.f, 0.f}};
  int* const myflag = &flags[((g * 16 + j) * 4 + w) * 16];

  // ---- per-wave x raw loads for t=0 (registers; converted in-loop)
  float xraw[2][3][8];
#pragma unroll
  for (int rg = 0; rg < 2; ++rg) {
    const float* xr = x + (size_t)(g * 32 + rg * 16 + srow) * (T_STEPS * D_IN);
#pragma unroll
    for (int kx = 0; kx < 3; ++kx)
#pragma unroll
      for (int e = 0; e < 8; ++e) {
        int d = kx * 32 + grp * 8 + e;
        xraw[rg][kx][e] = (d < D_IN) ? xr[d] : 0.f;
      }
  }

  // ---- publish h_0 = 0 (per-wave quarter), then flag=1
  {
    unsigned long long* hb0 = hbuf + (size_t)(0 * NG + g) * 4096;
    if (lane < 32) {
      int rg = lane >> 4, row = lane & 15;
      unsigned long long* dst = hb0 + (size_t)((rg * 16 + j) * 64 + (w * 16 + row)) * 2;
      AST(dst, 0ull);
      AST(dst + 1, 0ull);
    }
    asm volatile("s_waitcnt vmcnt(0)" ::: "memory");
    if (lane == 0) AST(myflag, 1);
  }

  for (int t = 0; t < T_STEPS; ++t) {
    // ---- poll all 64 producer-wave flags of group g (lane -> (j',w'))
    {
      const int tgt = t + 1;
      const int* fp = &flags[((g * 16 + (lane & 15)) * 4 + (lane >> 4)) * 16];
      while (true) {
        int f = ALD(fp);
        if (__all(f >= tgt)) break;
        __builtin_amdgcn_s_sleep(1);
      }
    }

    // ---- stage this wave's 8 chunks: issue all 16 ULL loads back-to-back
    const unsigned long long* hb = hbuf + (size_t)((t & 1) * NG + g) * 4096;
    union FR { unsigned long long u[2]; u32x4 q; } sv[8];
#pragma unroll
    for (int c8 = 0; c8 < 8; ++c8) {
      const unsigned long long* p = hb + (size_t)(w * 8 + c8) * 128 + lane * 2;
      sv[c8].u[0] = ALD(p);
      sv[c8].u[1] = ALD(p + 1);
    }

    // ---- convert this step's x frags from raw regs (VALU under load latency)
    short8 xf[2][3];
#pragma unroll
    for (int rg = 0; rg < 2; ++rg)
#pragma unroll
      for (int kx = 0; kx < 3; ++kx) {
        unsigned short vs[8];
#pragma unroll
        for (int e = 0; e < 8; ++e) vs[e] = f2b(xraw[rg][kx][e]);
        union { unsigned long long u[2]; short8 v; } q;
        q.u[0] = pack4(vs);
        q.u[1] = pack4(vs + 4);
        xf[rg][kx] = q.v;
      }

    // ---- regs -> LDS hstage as b128 stores (conflict-free lane*16B pattern)
#pragma unroll
    for (int c8 = 0; c8 < 8; ++c8)
      *(u32x4*)&sm.s.hstage[w * 8 + c8][lane][0] = sv[c8].q;

    // ---- issue x raw loads for t+1 (after the staging drain point, so the
    //      sv waitcnt never waits on these; they land during MFMA..poll)
    if (t + 1 < T_STEPS) {
      const int tn = t + 1;
#pragma unroll
      for (int rg = 0; rg < 2; ++rg) {
        const float* xr = x + (size_t)(g * 32 + rg * 16 + srow) * (T_STEPS * D_IN) + (size_t)tn * D_IN;
#pragma unroll
        for (int kx = 0; kx < 3; ++kx)
#pragma unroll
          for (int e = 0; e < 8; ++e) {
            int d = kx * 32 + grp * 8 + e;
            xraw[rg][kx][e] = (d < D_IN) ? xr[d] : 0.f;
          }
      }
    }

    __syncthreads();   // the ONE barrier per step

    // ---- MFMA: 6 x-tiles (reg frags) + 32 h-tiles (LDS)
    f32x4 acc[2][2];
#pragma unroll
    for (int ct = 0; ct < 2; ++ct)
#pragma unroll
      for (int rg = 0; rg < 2; ++rg)
        acc[ct][rg] = (f32x4){0.f, 0.f, 0.f, 0.f};

#pragma unroll
    for (int kx = 0; kx < 3; ++kx) {
      acc[0][0] = __builtin_amdgcn_mfma_f32_16x16x32_bf16(xf[0][kx], Wreg[0][16 + kx], acc[0][0], 0, 0, 0);
      acc[1][0] = __builtin_amdgcn_mfma_f32_16x16x32_bf16(xf[0][kx], Wreg[1][16 + kx], acc[1][0], 0, 0, 0);
      acc[0][1] = __builtin_amdgcn_mfma_f32_16x16x32_bf16(xf[1][kx], Wreg[0][16 + kx], acc[0][1], 0, 0, 0);
      acc[1][1] = __builtin_amdgcn_mfma_f32_16x16x32_bf16(xf[1][kx], Wreg[1][16 + kx], acc[1][1], 0, 0, 0);
    }
#pragma unroll
    for (int kk = 0; kk < 16; ++kk) {
      short8 a0 = *(const short8*)&sm.s.hstage[kk][lane][0];       // rg0
      short8 a1 = *(const short8*)&sm.s.hstage[16 + kk][lane][0];  // rg1
      acc[0][0] = __builtin_amdgcn_mfma_f32_16x16x32_bf16(a0, Wreg[0][kk], acc[0][0], 0, 0, 0);
      acc[1][0] = __builtin_amdgcn_mfma_f32_16x16x32_bf16(a0, Wreg[1][kk], acc[1][0], 0, 0, 0);
      acc[0][1] = __builtin_amdgcn_mfma_f32_16x16x32_bf16(a1, Wreg[0][kk], acc[0][1], 0, 0, 0);
      acc[1][1] = __builtin_amdgcn_mfma_f32_16x16x32_bf16(a1, Wreg[1][kk], acc[1][1], 0, 0, 0);
    }

    // ---- epilogue: in-wave LDS transpose, activations, c/h update
#pragma unroll
    for (int ct = 0; ct < 2; ++ct) {
      *(f32x4*)&sm.s.gatesT[w][ct][0][srow][grp * 4] = acc[ct][0];
      *(f32x4*)&sm.s.gatesT[w][ct][1][srow][grp * 4] = acc[ct][1];
    }
#pragma unroll
    for (int ct = 0; ct < 2; ++ct)
#pragma unroll
      for (int rg = 0; rg < 2; ++rg) {
        float vi = sm.s.gatesT[w][ct][rg][grp + 0][srow] + bias_[ct][0];
        float vf = sm.s.gatesT[w][ct][rg][grp + 4][srow] + bias_[ct][1];
        float vg = sm.s.gatesT[w][ct][rg][grp + 8][srow] + bias_[ct][2];
        float vo = sm.s.gatesT[w][ct][rg][grp + 12][srow] + bias_[ct][3];
        float ii = sigmf(vi), ff = sigmf(vf);
        float gg = tanhf_(vg), oo = sigmf(vo);
        float cn = ff * cst[ct][rg] + ii * gg;
        cst[ct][rg] = cn;
        float hh = oo * tanhf_(cn);
        sm.s.hq[w][rg][srow][ct * 4 + grp] = f2b(hh);
      }

    // ---- per-wave publish of h_{t+1} quarter + own flag
    {
      unsigned long long* hbn = hbuf + (size_t)(((t + 1) & 1) * NG + g) * 4096;
      if (lane < 32) {
        int rg = lane >> 4, row = lane & 15;
        const unsigned long long* hp = (const unsigned long long*)&sm.s.hq[w][rg][row][0];
        unsigned long long u0 = hp[0], u1 = hp[1];
        unsigned long long* dst = hbn + (size_t)((rg * 16 + j) * 64 + (w * 16 + row)) * 2;
        AST(dst, u0);
        AST(dst + 1, u1);
      }
      asm volatile("s_waitcnt vmcnt(0)" ::: "memory");
      if (lane == 0) AST(myflag, t + 2);
    }
  }

  // ---- final FC: z = h_T @ fc_w^T + fc_b  (j==0 blocks; h_T in parity 0)
  if (j == 0) {
    {
      const int tgt = T_STEPS + 1;
      const int* fp = &flags[((g * 16 + (lane & 15)) * 4 + (lane >> 4)) * 16];
      while (true) {
        int f = ALD(fp);
        if (__all(f >= tgt)) break;
        __builtin_amdgcn_s_sleep(1);
      }
    }
    __syncthreads();   // all waves past loop before zbuf overwrites the union
    const unsigned long long* hb0 = hbuf + (size_t)(0 * NG + g) * 4096;
    for (int it = tid; it < 2048; it += 256) {
      unsigned long long a = ALD(hb0 + it * 2);
      unsigned long long b = ALD(hb0 + it * 2 + 1);
      ((unsigned long long*)sm.zbuf)[it * 2] = a;
      ((unsigned long long*)sm.zbuf)[it * 2 + 1] = b;
    }
    __syncthreads();
    for (int i = tid; i < 32 * NCLS_; i += 256) {
      int r = i / NCLS_, n = i % NCLS_;
      float s = fc_b[n];
      const float* fw = fc_w + n * H_DIM;
      int rg = r >> 4, rr = r & 15;
      for (int k = 0; k < H_DIM; ++k) {
        int kk = k >> 5, lch = rr + (((k >> 3) & 3) << 4), e = k & 7;
        unsigned short hu = ((const unsigned short*)sm.zbuf)[(((rg * 16 + kk) * 64 + lch) << 3) + e];
        s += b2f(hu) * fw[k];
      }
      out[(g * 32 + r) * NCLS_ + n] = s;
    }
  }
}

// ---------------------------------------------------------------------------
extern "C" void kernel_launch(void* const* d_in, const int* in_sizes, int n_in,
                              void* d_out, int out_size, void* d_ws, size_t ws_size,
                              hipStream_t stream) {
  const float* x       = (const float*)d_in[0];
  const float* wih_mu  = (const float*)d_in[1];
  const float* wih_rho = (const float*)d_in[2];
  const float* eps_ih  = (const float*)d_in[3];
  const float* whh_mu  = (const float*)d_in[4];
  const float* whh_rho = (const float*)d_in[5];
  const float* eps_hh  = (const float*)d_in[6];
  const float* b_mu    = (const float*)d_in[7];
  const float* b_rho   = (const float*)d_in[8];
  const float* eps_b   = (const float*)d_in[9];
  const float* fc_w    = (const float*)d_in[10];
  const float* fc_b    = (const float*)d_in[11];

  // ws layout: wpack [0, 2490368) | hbuf [2490368, 3014656) | flags [3014656, +32768)
  unsigned short* wpack = (unsigned short*)d_ws;
  unsigned long long* hbuf = (unsigned long long*)((char*)d_ws + 2490368);
  int* flags = (int*)((char*)d_ws + 3014656);

  hipMemsetAsync(flags, 0, 32768, stream);
  pack_w_kernel<<<NJ * 8 * NKK, 64, 0, stream>>>(wih_mu, wih_rho, eps_ih,
                                                 whh_mu, whh_rho, eps_hh, wpack);
  lstm_scan_kernel<<<NG * NJ, 256, 0, stream>>>(x, wpack, b_mu, b_rho, eps_b,
                                                fc_w, fc_b, hbuf, flags,
                                                (float*)d_out);
}